// Round 1
// baseline (306.856 us; speedup 1.0000x reference)
//
#include <hip/hip_runtime.h>
#include <hip/hip_cooperative_groups.h>

namespace cg = cooperative_groups;

// B=32, S=2048, I=128, H=512, O=64, R=1, ALPHA=0.1  (rank-1 scalar-state RNN)
// Fused single cooperative kernel, 4 phases separated by grid.sync():
//   U: u[b,t] = x[b,t,:].irc ; pack W^T -> bf16 MFMA B-frags
//   V: v_t = 0.9 v + 0.1 sum_h rr[h]*relu(v*rp[h] + u_t*ip[h])   (chunk-32, 96 warm-up)
//   W: w_t[o] = sum_h W[o,h]*relu(V_t*rp[h] + u_t*ip[h])         (bf16 MFMA)
//   Y: y_t = 0.9 y + 0.1 w_t ; out = y + bias                    (chunk-32, 96 warm-up)
// Grid 512 x 256: 2 blocks/CU (64 KB LDS each), 8 waves/CU. Replaces 4 kernel
// launches (theory: dispatch serialization was ~120 of 151 us).

#define B_ 32
#define S_ 2048
#define I_ 128
#define H_ 512
#define O_ 64

typedef __attribute__((ext_vector_type(8))) short bf16x8;
typedef __attribute__((ext_vector_type(4))) float f32x4;

__device__ __forceinline__ unsigned short f2bf(float f) {
  unsigned int b = __float_as_uint(f);
  b += 0x7FFFu + ((b >> 16) & 1u);
  return (unsigned short)(b >> 16);
}
__device__ __forceinline__ float bf2f(unsigned short s) {
  return __uint_as_float(((unsigned)s) << 16);
}
__device__ __forceinline__ unsigned pack_bf(float lo, float hi) {
  unsigned a = (__float_as_uint(lo) + 0x8000u) >> 16;
  unsigned b = (__float_as_uint(hi) + 0x8000u) & 0xFFFF0000u;
  return a | b;
}

// DPP row-rotate add: after ror 1,2,4,8 every lane holds its 16-lane row sum.
#define ROR_ADD(s, CTRL) \
  s += __int_as_float(__builtin_amdgcn_update_dpp(0, __float_as_int(s), CTRL, 0xF, 0xF, true))

union SMem {
  float su[4][128];            // phase V: per-wave u window (2 KB)
  unsigned short bf[32768];    // phase W: W^T bf16 B-fragments (64 KB)
  unsigned short wt[4][8192];  // phase Y: per-wave w window (64 KB)
};

__global__ __launch_bounds__(256, 2) void k_fused(
    const float* __restrict__ x, const float* __restrict__ ipj,
    const float* __restrict__ irc, const float* __restrict__ rpj,
    const float* __restrict__ rrc, const float* __restrict__ W,
    const float* __restrict__ bias, float* __restrict__ out,
    float* __restrict__ u, float* __restrict__ V,
    unsigned short* __restrict__ BF, unsigned short* __restrict__ wbuf,
    int phase) {
  __shared__ SMem sm;
  cg::grid_group grid = cg::this_grid();
  const int tid = threadIdx.x;
  const int wv = tid >> 6;
  const int lane = tid & 63;
  const int wid = blockIdx.x * 4 + wv;  // 0..2047
  const bool all = (phase < 0);

  // ---------------- Phase U: u[row] = x[row,:].irc (32 rows/wave) + BF pack
  if (all || phase == 0) {
    float2 cv = ((const float2*)irc)[lane];
    int row0 = wid * 32;
    #pragma unroll 4
    for (int r = 0; r < 32; r++) {
      int row = row0 + r;
      float2 xv = ((const float2*)(x + (size_t)row * I_))[lane];
      float s = fmaf(xv.x, cv.x, xv.y * cv.y);
      #pragma unroll
      for (int off = 32; off; off >>= 1) s += __shfl_xor(s, off, 64);
      if (lane == 0) u[row] = s;
    }
    // W^T -> MFMA B-frag order: BF[((kt*4+ot)*64+lane)*8+j] = W[(ot*16+(lane&15))*H + kt*32+(lane>>4)*8+j]
    int gtid = blockIdx.x * 256 + tid;
    if (gtid < 32768) {
      int j = gtid & 7, l2 = (gtid >> 3) & 63, ot = (gtid >> 9) & 3, kt = gtid >> 11;
      int o = ot * 16 + (l2 & 15);
      int h = kt * 32 + (l2 >> 4) * 8 + j;
      BF[gtid] = f2bf(W[o * H_ + h]);
    }
  }
  if (all) grid.sync();

  // ---------------- Phase V: chunk-32 scalar scan, 128 uniform steps (96 warm-up)
  if (all || phase == 1) {
    int b = wid >> 6, c = wid & 63;
    float rpv[8], ipv[8], rrv[8];
    #pragma unroll
    for (int k = 0; k < 8; k++) {
      int h = lane + 64 * k;
      rpv[k] = rpj[h]; ipv[k] = ipj[h]; rrv[k] = rrc[h];
    }
    int real0 = c * 32;
    int t0 = real0 - 96;
    const float* ub = u + b * S_;
    int ta = t0 + lane, tb = t0 + 64 + lane;
    sm.su[wv][lane]      = (ta >= 0) ? ub[ta] : 0.f;
    sm.su[wv][lane + 64] = (tb >= 0) ? ub[tb] : 0.f;
    __syncthreads();
    float v = 0.f;
    float* Vb = V + b * S_ + real0;
    #pragma unroll 8
    for (int i = 0; i < 128; i++) {
      if (i >= 96 && lane == 0) Vb[i - 96] = v;   // V[b][t] = v entering step t
      float ut = sm.su[wv][i];
      float q0 = fmaxf(fmaf(v, rpv[0], ut * ipv[0]), 0.f) * rrv[0];
      float q1 = fmaxf(fmaf(v, rpv[1], ut * ipv[1]), 0.f) * rrv[1];
      float q2 = fmaxf(fmaf(v, rpv[2], ut * ipv[2]), 0.f) * rrv[2];
      float q3 = fmaxf(fmaf(v, rpv[3], ut * ipv[3]), 0.f) * rrv[3];
      float q4 = fmaxf(fmaf(v, rpv[4], ut * ipv[4]), 0.f) * rrv[4];
      float q5 = fmaxf(fmaf(v, rpv[5], ut * ipv[5]), 0.f) * rrv[5];
      float q6 = fmaxf(fmaf(v, rpv[6], ut * ipv[6]), 0.f) * rrv[6];
      float q7 = fmaxf(fmaf(v, rpv[7], ut * ipv[7]), 0.f) * rrv[7];
      float s = ((q0 + q1) + (q2 + q3)) + ((q4 + q5) + (q6 + q7));
      ROR_ADD(s, 0x121); ROR_ADD(s, 0x122); ROR_ADD(s, 0x124); ROR_ADD(s, 0x128);
      float tot = __int_as_float(__builtin_amdgcn_readlane(__float_as_int(s), 0)) +
                  __int_as_float(__builtin_amdgcn_readlane(__float_as_int(s), 16)) +
                  __int_as_float(__builtin_amdgcn_readlane(__float_as_int(s), 32)) +
                  __int_as_float(__builtin_amdgcn_readlane(__float_as_int(s), 48));
      v = fmaf(0.9f, v, 0.1f * tot);
    }
  }
  if (all) grid.sync();

  // ---------------- Phase W: w = relu(V*rp + u*ipj) @ W^T via 16x16x32 bf16 MFMA
  // 128 rows/block (2 m-tiles/wave); BF staged once to LDS, B-frags register-reused.
  if (all || phase == 2) {
    {
      const uint4* s4 = (const uint4*)BF;
      uint4* d4 = (uint4*)sm.bf;
      #pragma unroll
      for (int i = 0; i < 16; i++) d4[tid + 256 * i] = s4[tid + 256 * i];
    }
    __syncthreads();
    int tl = lane & 15, quad = lane >> 4;
    int row0 = blockIdx.x * 128 + wv * 32;
    float Vr[2], ur[2];
    #pragma unroll
    for (int mt = 0; mt < 2; mt++) {
      Vr[mt] = V[row0 + mt * 16 + tl];
      ur[mt] = u[row0 + mt * 16 + tl];
    }
    f32x4 acc[2][4] = {};   // [mt][ot]
    #pragma unroll 4
    for (int kt = 0; kt < 16; kt++) {
      int hbase = kt * 32 + quad * 8;
      f32x4 rp4a = *(const f32x4*)(rpj + hbase);
      f32x4 rp4b = *(const f32x4*)(rpj + hbase + 4);
      f32x4 ip4a = *(const f32x4*)(ipj + hbase);
      f32x4 ip4b = *(const f32x4*)(ipj + hbase + 4);
      bf16x8 bfr[4];
      #pragma unroll
      for (int ot = 0; ot < 4; ot++)
        bfr[ot] = *(const bf16x8*)(sm.bf + (((kt * 4 + ot) * 64 + lane) << 3));
      #pragma unroll
      for (int mt = 0; mt < 2; mt++) {
        float q[8];
        #pragma unroll
        for (int j = 0; j < 4; j++) {
          q[j]     = fmaxf(fmaf(Vr[mt], rp4a[j], ur[mt] * ip4a[j]), 0.f);
          q[4 + j] = fmaxf(fmaf(Vr[mt], rp4b[j], ur[mt] * ip4b[j]), 0.f);
        }
        union { bf16x8 v; unsigned w[4]; } a;
        #pragma unroll
        for (int j = 0; j < 4; j++) a.w[j] = pack_bf(q[2 * j], q[2 * j + 1]);
        #pragma unroll
        for (int ot = 0; ot < 4; ot++)
          acc[mt][ot] = __builtin_amdgcn_mfma_f32_16x16x32_bf16(a.v, bfr[ot], acc[mt][ot], 0, 0, 0);
      }
    }
    // C/D layout: col = ot*16 + (lane&15), row = quad*4 + r
    #pragma unroll
    for (int mt = 0; mt < 2; mt++) {
      int rbase = row0 + mt * 16 + quad * 4;
      #pragma unroll
      for (int r = 0; r < 4; r++) {
        #pragma unroll
        for (int ot = 0; ot < 4; ot++)
          wbuf[(size_t)(rbase + r) * O_ + ot * 16 + tl] = f2bf(acc[mt][ot][r]);
      }
    }
  }
  if (all) grid.sync();

  // ---------------- Phase Y: chunk-32 readout scan (96 warm-up), 1 wave/chunk
  if (all || phase == 3) {
    int b = wid >> 6, c = wid & 63;
    int real0 = c * 32;
    int t0 = real0 - 96; if (t0 < 0) t0 = 0;
    int n = real0 + 32 - t0;          // <= 128
    int warm = real0 - t0;
    const uint4* src = (const uint4*)(wbuf + (size_t)(b * S_ + t0) * O_);
    uint4* dst = (uint4*)(&sm.wt[wv][0]);
    int total16 = n * 8;
    for (int i = lane; i < total16; i += 64) dst[i] = src[i];
    __syncthreads();
    float y = 0.f;
    float bo = bias[lane];
    float* ob = out + ((size_t)(b * S_ + real0)) * O_ + lane;
    const unsigned short* wl = &sm.wt[wv][0] + lane;
    for (int t = 0; t < n; t++) {
      float wvv = bf2f(wl[t * 64]);
      y = fmaf(0.9f, y, 0.1f * wvv);
      if (t >= warm) ob[(size_t)(t - warm) * O_] = y + bo;
    }
  }
}

extern "C" void kernel_launch(void* const* d_in, const int* in_sizes, int n_in,
                              void* d_out, int out_size, void* d_ws, size_t ws_size,
                              hipStream_t stream) {
  const float* x   = (const float*)d_in[0];
  const float* ipj = (const float*)d_in[1];
  const float* irc = (const float*)d_in[2];
  const float* rpj = (const float*)d_in[3];
  const float* rrc = (const float*)d_in[4];
  const float* Wr  = (const float*)d_in[5];
  const float* br  = (const float*)d_in[6];
  float* out = (float*)d_out;

  char* ws = (char*)d_ws;
  float* u            = (float*)(ws);                         // 256 KB
  float* V            = (float*)(ws + (256 << 10));           // 256 KB
  unsigned short* BF  = (unsigned short*)(ws + (512 << 10));  // 64 KB
  unsigned short* wbf = (unsigned short*)(ws + (1024 << 10)); // 8 MB

  int phase = -1;
  void* args[] = {(void*)&x, (void*)&ipj, (void*)&irc, (void*)&rpj, (void*)&rrc,
                  (void*)&Wr, (void*)&br, (void*)&out, (void*)&u, (void*)&V,
                  (void*)&BF, (void*)&wbf, (void*)&phase};
  hipError_t e = hipLaunchCooperativeKernel((const void*)k_fused, dim3(512), dim3(256),
                                            args, 0, stream);
  if (e != hipSuccess) {
    // Fallback: run the same kernel phase-by-phase as 4 ordinary launches
    // (grid.sync() calls are skipped when phase >= 0).
    for (int p = 0; p < 4; p++)
      hipLaunchKernelGGL(k_fused, dim3(512), dim3(256), 0, stream,
                         x, ipj, irc, rpj, rrc, Wr, br, out, u, V, BF, wbf, p);
  }
}

// Round 2
// 197.361 us; speedup vs baseline: 1.5548x; 1.5548x over previous
//
#include <hip/hip_runtime.h>

// B=32, S=2048, I=128, H=512, O=64, R=1, ALPHA=0.1  (rank-1 scalar-state RNN)
// SINGLE ordinary dispatch (no grid.sync - round 1 showed cooperative sync costs
// ~60us each on gfx950's 8 non-coherent XCDs). 256 blocks x 256 threads; each
// block owns 256 output timesteps of one batch and recomputes its own warm-up:
//   ph1: u[t] = x[t,:].irc for t in [r0-192, r0+256)  (shfl-reduce, verified)
//        + pack W^T -> bf16 MFMA B-frags in LDS (from global W, L2-hot)
//   ph2: 4 waves x 88-t V-chunks, 96-step warm-up, 184 uniform steps (verified body)
//   ph3: w[t][o] = relu(V*rp+u*ip) @ W^T for 352 rows via 16x16x32 bf16 MFMA -> LDS
//   ph4: y_t = 0.9 y + 0.1 w_t ; out = y + bias  (96-step warm-up, w rows t<0 are 0)
// Only __syncthreads() between phases. No workspace traffic at all.

#define B_ 32
#define S_ 2048
#define I_ 128
#define H_ 512
#define O_ 64

typedef __attribute__((ext_vector_type(8))) short bf16x8;
typedef __attribute__((ext_vector_type(4))) float f32x4;

__device__ __forceinline__ unsigned short f2bf(float f) {
  unsigned int b = __float_as_uint(f);
  b += 0x7FFFu + ((b >> 16) & 1u);
  return (unsigned short)(b >> 16);
}
__device__ __forceinline__ float bf2f(unsigned short s) {
  return __uint_as_float(((unsigned)s) << 16);
}
__device__ __forceinline__ unsigned pack_bf(float lo, float hi) {
  unsigned a = (__float_as_uint(lo) + 0x8000u) >> 16;
  unsigned b = (__float_as_uint(hi) + 0x8000u) & 0xFFFF0000u;
  return a | b;
}

// DPP row-rotate add: after ror 1,2,4,8 every lane holds its 16-lane row sum.
#define ROR_ADD(s, CTRL) \
  s += __int_as_float(__builtin_amdgcn_update_dpp(0, __float_as_int(s), CTRL, 0xF, 0xF, true))

// LDS layout (dynamic, 118144 B):
//   float su[480];    u for t in [r0-192, r0+256), +32 zero pad
//   float sV[384];    V for t in [r0-96,  r0+256), +32 zero pad
//   float srp[512], sip[512];
//   ushort sBF[32768];     W^T bf16 B-frags (64 KB)
//   ushort sw[352*64];     w bf16 rows [r0-96, r0+256)  (45 KB)
#define SMEM_BYTES ((480 + 384 + 512 + 512) * 4 + (32768 + 352 * 64) * 2)

// sw bank-swizzle: row stride is 128 B so quads would collide on banks 0-7;
// XOR col bits 4-5 with (row>>2)&3 (== quad in ph3) spreads quads across banks.
__device__ __forceinline__ int swz(int row, int col) {
  return row * 64 + (col ^ ((((unsigned)row >> 2) & 3) << 4));
}

__global__ __launch_bounds__(256, 1) void k_fused(
    const float* __restrict__ x, const float* __restrict__ ipj,
    const float* __restrict__ irc, const float* __restrict__ rpj,
    const float* __restrict__ rrc, const float* __restrict__ Wr,
    const float* __restrict__ bias, float* __restrict__ out) {
  extern __shared__ __align__(16) char smem[];
  float* su = (float*)smem;                           // 480
  float* sV = su + 480;                               // 384
  float* srp = sV + 384;                              // 512
  float* sip = srp + 512;                             // 512
  unsigned short* sBF = (unsigned short*)(sip + 512); // 32768
  unsigned short* sw = sBF + 32768;                   // 22528

  const int tid = threadIdx.x;
  const int wv = tid >> 6;
  const int lane = tid & 63;
  const int b = blockIdx.x >> 3;
  const int g = blockIdx.x & 7;
  const int r0 = g * 256;

  // Preload phase-2 per-lane params from global (latency hides under phase 1).
  float rpv[8], ipv[8], rrv[8];
  #pragma unroll
  for (int k = 0; k < 8; k++) {
    int h = lane + 64 * k;
    rpv[k] = rpj[h]; ipv[k] = ipj[h]; rrv[k] = rrc[h];
  }

  // ---------------- Phase 1a: stage rp/ip to LDS, zero pads
  srp[tid] = rpj[tid]; srp[tid + 256] = rpj[tid + 256];
  sip[tid] = ipj[tid]; sip[tid + 256] = ipj[tid + 256];
  if (tid < 32) { su[448 + tid] = 0.f; sV[352 + tid] = 0.f; }

  // ---------------- Phase 1b: u window [r0-192, r0+256) -> su  (112 rows/wave)
  {
    float2 cv = ((const float2*)irc)[lane];
    #pragma unroll 4
    for (int j = 0; j < 112; j++) {
      int k = wv * 112 + j;
      int t = r0 - 192 + k;
      float s = 0.f;
      if (t >= 0) {  // wave-uniform branch
        float2 xv = ((const float2*)(x + (size_t)(b * S_ + t) * I_))[lane];
        s = fmaf(xv.x, cv.x, xv.y * cv.y);
        #pragma unroll
        for (int off = 32; off; off >>= 1) s += __shfl_xor(s, off, 64);
      }
      if (lane == 0) su[k] = s;
    }
  }

  // ---------------- Phase 1c: pack W^T -> sBF (same frag map as verified k_ubf):
  // sBF[((kt*4+ot)*64+l2)*8+j] = bf(W[(ot*16+(l2&15))*H + kt*32+(l2>>4)*8+j])
  #pragma unroll 4
  for (int m = 0; m < 16; m++) {
    int seg = tid + 256 * m;                 // 0..4095
    int l2 = seg & 63, ot = (seg >> 6) & 3, kt = seg >> 8;
    int o = ot * 16 + (l2 & 15);
    int h0 = kt * 32 + (l2 >> 4) * 8;
    const float4* wp = (const float4*)(Wr + (size_t)o * H_ + h0);
    float4 wa = wp[0], wb = wp[1];
    uint4 pk;
    pk.x = (unsigned)f2bf(wa.x) | ((unsigned)f2bf(wa.y) << 16);
    pk.y = (unsigned)f2bf(wa.z) | ((unsigned)f2bf(wa.w) << 16);
    pk.z = (unsigned)f2bf(wb.x) | ((unsigned)f2bf(wb.y) << 16);
    pk.w = (unsigned)f2bf(wb.z) | ((unsigned)f2bf(wb.w) << 16);
    *(uint4*)(sBF + seg * 8) = pk;
  }
  __syncthreads();

  // ---------------- Phase 2: V-scan. Wave wv covers V rows [wv*88, wv*88+88)
  // of sV (t = r0-96+row); scan starts 96 earlier: su index = wv*88 + i.
  {
    float v = 0.f;
    int base = wv * 88;
    #pragma unroll 8
    for (int i = 0; i < 184; i++) {
      if (i >= 96 && lane == 0) sV[base + i - 96] = v;  // V entering step t
      float ut = su[base + i];
      float q0 = fmaxf(fmaf(v, rpv[0], ut * ipv[0]), 0.f) * rrv[0];
      float q1 = fmaxf(fmaf(v, rpv[1], ut * ipv[1]), 0.f) * rrv[1];
      float q2 = fmaxf(fmaf(v, rpv[2], ut * ipv[2]), 0.f) * rrv[2];
      float q3 = fmaxf(fmaf(v, rpv[3], ut * ipv[3]), 0.f) * rrv[3];
      float q4 = fmaxf(fmaf(v, rpv[4], ut * ipv[4]), 0.f) * rrv[4];
      float q5 = fmaxf(fmaf(v, rpv[5], ut * ipv[5]), 0.f) * rrv[5];
      float q6 = fmaxf(fmaf(v, rpv[6], ut * ipv[6]), 0.f) * rrv[6];
      float q7 = fmaxf(fmaf(v, rpv[7], ut * ipv[7]), 0.f) * rrv[7];
      float s = ((q0 + q1) + (q2 + q3)) + ((q4 + q5) + (q6 + q7));
      ROR_ADD(s, 0x121); ROR_ADD(s, 0x122); ROR_ADD(s, 0x124); ROR_ADD(s, 0x128);
      float tot = __int_as_float(__builtin_amdgcn_readlane(__float_as_int(s), 0)) +
                  __int_as_float(__builtin_amdgcn_readlane(__float_as_int(s), 16)) +
                  __int_as_float(__builtin_amdgcn_readlane(__float_as_int(s), 32)) +
                  __int_as_float(__builtin_amdgcn_readlane(__float_as_int(s), 48));
      v = fmaf(0.9f, v, 0.1f * tot);
    }
  }
  __syncthreads();

  // ---------------- Phase 3: w rows [0,352) (= t in [r0-96, r0+256)) via MFMA.
  // Every wave computes 6 m-tiles (tiles 22,23 read zero pad; stores skipped).
  {
    int tl = lane & 15, quad = lane >> 4;
    float Vr[6], ur[6];
    #pragma unroll
    for (int m = 0; m < 6; m++) {
      int row = (wv * 6 + m) * 16 + tl;   // 0..383
      Vr[m] = sV[row];
      ur[m] = su[96 + row];
    }
    f32x4 acc[6][4] = {};  // [m][ot]
    #pragma unroll 4
    for (int kt = 0; kt < 16; kt++) {
      int hbase = kt * 32 + quad * 8;
      f32x4 rp4a = *(const f32x4*)(srp + hbase);
      f32x4 rp4b = *(const f32x4*)(srp + hbase + 4);
      f32x4 ip4a = *(const f32x4*)(sip + hbase);
      f32x4 ip4b = *(const f32x4*)(sip + hbase + 4);
      bf16x8 bfr[4];
      #pragma unroll
      for (int ot = 0; ot < 4; ot++)
        bfr[ot] = *(const bf16x8*)(sBF + (((kt * 4 + ot) * 64 + lane) << 3));
      #pragma unroll
      for (int m = 0; m < 6; m++) {
        float q[8];
        #pragma unroll
        for (int j = 0; j < 4; j++) {
          q[j]     = fmaxf(fmaf(Vr[m], rp4a[j], ur[m] * ip4a[j]), 0.f);
          q[4 + j] = fmaxf(fmaf(Vr[m], rp4b[j], ur[m] * ip4b[j]), 0.f);
        }
        union { bf16x8 v; unsigned w[4]; } a;
        #pragma unroll
        for (int j = 0; j < 4; j++) a.w[j] = pack_bf(q[2 * j], q[2 * j + 1]);
        #pragma unroll
        for (int ot = 0; ot < 4; ot++)
          acc[m][ot] = __builtin_amdgcn_mfma_f32_16x16x32_bf16(a.v, bfr[ot], acc[m][ot], 0, 0, 0);
      }
    }
    // C/D layout: col = ot*16 + tl (o), row-in-tile = quad*4 + r (t offset)
    #pragma unroll
    for (int m = 0; m < 6; m++) {
      int mt = wv * 6 + m;
      if (mt < 22) {
        int rbase = mt * 16 + quad * 4;
        #pragma unroll
        for (int r = 0; r < 4; r++) {
          #pragma unroll
          for (int ot = 0; ot < 4; ot++)
            sw[swz(rbase + r, ot * 16 + tl)] = f2bf(acc[m][ot][r]);
        }
      }
    }
  }
  __syncthreads();

  // ---------------- Phase 4: y-scan. Wave wv owns outputs [r0+wv*64, +64);
  // scan sw rows [wv*64, wv*64+160) (rows with t<0 are exactly 0 -> uniform loop).
  {
    float y = 0.f;
    float bo = bias[lane];
    int k0 = wv * 64;
    float* ob = out + ((size_t)(b * S_ + r0 + wv * 64)) * O_ + lane;
    #pragma unroll 8
    for (int i = 0; i < 160; i++) {
      int row = k0 + i;
      float wval = bf2f(sw[swz(row, lane)]);
      y = fmaf(0.9f, y, 0.1f * wval);
      if (i >= 96) ob[(size_t)(i - 96) * O_] = y + bo;
    }
  }
}

extern "C" void kernel_launch(void* const* d_in, const int* in_sizes, int n_in,
                              void* d_out, int out_size, void* d_ws, size_t ws_size,
                              hipStream_t stream) {
  const float* x   = (const float*)d_in[0];
  const float* ipj = (const float*)d_in[1];
  const float* irc = (const float*)d_in[2];
  const float* rpj = (const float*)d_in[3];
  const float* rrc = (const float*)d_in[4];
  const float* Wr  = (const float*)d_in[5];
  const float* br  = (const float*)d_in[6];
  float* out = (float*)d_out;

  static bool s_init = false;
  if (!s_init) {
    hipFuncSetAttribute((const void*)k_fused,
                        hipFuncAttributeMaxDynamicSharedMemorySize, SMEM_BYTES);
    s_init = true;
  }
  k_fused<<<dim3(256), dim3(256), SMEM_BYTES, stream>>>(x, ipj, irc, rpj, rrc,
                                                        Wr, br, out);
}

// Round 3
// 149.286 us; speedup vs baseline: 2.0555x; 1.3220x over previous
//
#include <hip/hip_runtime.h>

// B=32, S=2048, I=128, H=512, O=64, R=1, ALPHA=0.1  (rank-1 scalar-state RNN)
// Single ordinary dispatch, 256 blocks x 512 threads (8 waves), 1 block/CU.
// Block owns 256 output timesteps of one batch; recomputes 96-step warm-up.
//   ph1: x window [r0-192,r0+256) staged to LDS in 7x64-row chunks (coalesced
//        float4, double-buffered); 8-lane/row dot -> su. W^T packed -> sBF.
//   ph2: 8 waves x 44-t V-chunks, 96-step warm-up (140 uniform steps), f32x2 packed
//   ph3: w rows [0,352) = relu(V*rp+u*ip) @ W^T via 16x16x32 bf16 MFMA -> sw
//   ph4: y-scan, 8 waves x 32 outputs, 96-step warm-up (rows t<0 are zero)
// Round-2 lesson: branchy per-row loads + 6-deep shfl chains in ph1b exposed
// ~100us of latency; this round makes staging throughput-shaped.

#define B_ 32
#define S_ 2048
#define I_ 128
#define H_ 512
#define O_ 64

typedef __attribute__((ext_vector_type(8))) short bf16x8;
typedef __attribute__((ext_vector_type(4))) float f32x4;
typedef __attribute__((ext_vector_type(2))) float f32x2;

__device__ __forceinline__ unsigned short f2bf(float f) {
  unsigned int b = __float_as_uint(f);
  b += 0x7FFFu + ((b >> 16) & 1u);
  return (unsigned short)(b >> 16);
}
__device__ __forceinline__ float bf2f(unsigned short s) {
  return __uint_as_float(((unsigned)s) << 16);
}
__device__ __forceinline__ unsigned pack_bf(float lo, float hi) {
  unsigned a = (__float_as_uint(lo) + 0x8000u) >> 16;
  unsigned b = (__float_as_uint(hi) + 0x8000u) & 0xFFFF0000u;
  return a | b;
}

// DPP row-rotate add (within 16-lane row). ror 1,2,4,8 = full 16-row sum in
// every lane; ror 1,2,4 = 8-sum valid at in-row positions 7 and 15.
#define ROR_ADD(s, CTRL) \
  s += __int_as_float(__builtin_amdgcn_update_dpp(0, __float_as_int(s), CTRL, 0xF, 0xF, true))

// LDS layout (118144 B):
//   float su[480]; float sV[384]; float srp[512]; float sip[512];   (7552 B)
//   ushort sBF[32768] (64 KB)  |  ushort sw[352*64] (45 KB)
//   ph1 x-staging scratch (2 x 64 x 132 floats = 67.6 KB) aliases sBF + sw head.
#define SMEM_BYTES ((480 + 384 + 512 + 512) * 4 + (32768 + 352 * 64) * 2)

// sw bank-swizzle (verified r0/r2): row stride 128 B; XOR col bits 4-5 with
// (row>>2)&3 (== quad in ph3) spreads quads across banks.
__device__ __forceinline__ int swz(int row, int col) {
  return row * 64 + (col ^ ((((unsigned)row >> 2) & 3) << 4));
}

__global__ __launch_bounds__(512, 1) void k_fused(
    const float* __restrict__ x, const float* __restrict__ ipj,
    const float* __restrict__ irc, const float* __restrict__ rpj,
    const float* __restrict__ rrc, const float* __restrict__ Wr,
    const float* __restrict__ bias, float* __restrict__ out) {
  extern __shared__ __align__(16) char smem[];
  float* su = (float*)smem;                           // 480
  float* sV = su + 480;                               // 384
  float* srp = sV + 384;                              // 512
  float* sip = srp + 512;                             // 512
  unsigned short* sBF = (unsigned short*)(sip + 512); // 32768 ushorts
  unsigned short* sw = sBF + 32768;                   // 22528 ushorts
  float* scratch = (float*)sBF;                       // ph1 staging (2 x 8448 f)

  const int tid = threadIdx.x;
  const int wv = tid >> 6;      // 0..7
  const int lane = tid & 63;
  const int b = blockIdx.x >> 3;
  const int g = blockIdx.x & 7;
  const int r0 = g * 256;

  // ---- top-of-kernel preloads (latency hides under ph1 staging) ----
  // ph2 per-lane params as f32x2 pairs: h = 2*(lane+64k), 2*(lane+64k)+1
  f32x2 rp2[4], ip2[4], rr2[4];
  #pragma unroll
  for (int k = 0; k < 4; k++) {
    float2 a = ((const float2*)rpj)[lane + 64 * k];
    float2 c = ((const float2*)ipj)[lane + 64 * k];
    float2 d = ((const float2*)rrc)[lane + 64 * k];
    rp2[k] = f32x2{a.x, a.y}; ip2[k] = f32x2{c.x, c.y}; rr2[k] = f32x2{d.x, d.y};
  }
  // ph1 per-lane irc slice: eighth e = lane&7, cols [e*16, e*16+16)
  f32x4 cvq[4];
  #pragma unroll
  for (int i = 0; i < 4; i++)
    cvq[i] = *(const f32x4*)(irc + (lane & 7) * 16 + i * 4);

  // stage rp/ip to LDS for ph3; zero pads (read by ph3 tiles 22/23, discarded)
  srp[tid] = rpj[tid];
  sip[tid] = ipj[tid];
  if (tid < 32) { su[448 + tid] = 0.f; sV[352 + tid] = 0.f; }

  // ---------------- Phase 1: x-window dot -> su, 7 chunks of 64 rows ----------
  // chunk c: t in [r0-192+c*64, +64). For g==0, chunks 0-2 are fully negative
  // (mask=0; loads clamped to row 0 -> harmless).
  auto LOADX = [&](float4* d, int c) {
    int tc0 = r0 - 192 + c * 64;
    int tcl = tc0 < 0 ? 0 : tc0;
    const float4* src = (const float4*)(x + ((size_t)b * S_ + tcl) * I_);
    #pragma unroll
    for (int j = 0; j < 4; j++) d[j] = src[tid + 512 * j];
  };
  auto STOREX = [&](const float4* v, int c) {
    float* bufc = scratch + (c & 1) * 8448;
    #pragma unroll
    for (int j = 0; j < 4; j++) {
      int q = tid + 512 * j;                     // 0..2047 float4s
      *(float4*)(bufc + (q >> 5) * 132 + (q & 31) * 4) = v[j];
    }
  };
  auto COMPUTE = [&](int c) {
    const float* bufc = scratch + (c & 1) * 8448;
    int tc0 = r0 - 192 + c * 64;
    float mask = tc0 < 0 ? 0.f : 1.f;
    const float* bp = bufc + (wv * 8 + (lane >> 3)) * 132 + (lane & 7) * 16;
    float a0 = 0.f, a1 = 0.f;
    #pragma unroll
    for (int i = 0; i < 4; i++) {
      f32x4 xv = *(const f32x4*)(bp + 4 * i);
      a0 = fmaf(xv[0], cvq[i][0], a0);
      a1 = fmaf(xv[1], cvq[i][1], a1);
      a0 = fmaf(xv[2], cvq[i][2], a0);
      a1 = fmaf(xv[3], cvq[i][3], a1);
    }
    float s = a0 + a1;
    ROR_ADD(s, 0x121); ROR_ADD(s, 0x122); ROR_ADD(s, 0x124);  // 8-lane sums
    if ((lane & 7) == 7) su[c * 64 + wv * 8 + (lane >> 3)] = s * mask;
  };

  float4 ra[4], rb[4];
  LOADX(ra, 0);
  #pragma unroll
  for (int c = 0; c < 7; c++) {
    if (c & 1) { STOREX(rb, c); if (c < 6) LOADX(ra, c + 1); }
    else       { STOREX(ra, c); if (c < 6) LOADX(rb, c + 1); }
    __syncthreads();      // chunk c staged for all waves
    COMPUTE(c);           // reads buf[c&1]; next store hits buf[(c+1)&1]
  }
  __syncthreads();        // su complete; scratch dead -> sBF reusable

  // ---------------- Phase 1c: pack W^T -> sBF (verified frag map):
  // sBF[((kt*4+ot)*64+l2)*8+j] = bf(W[(ot*16+(l2&15))*H + kt*32+(l2>>4)*8+j])
  #pragma unroll 4
  for (int m = 0; m < 8; m++) {
    int seg = tid + 512 * m;                 // 0..4095
    int l2 = seg & 63, ot = (seg >> 6) & 3, kt = seg >> 8;
    int o = ot * 16 + (l2 & 15);
    int h0 = kt * 32 + (l2 >> 4) * 8;
    const float4* wp = (const float4*)(Wr + (size_t)o * H_ + h0);
    float4 wa = wp[0], wb = wp[1];
    uint4 pk;
    pk.x = (unsigned)f2bf(wa.x) | ((unsigned)f2bf(wa.y) << 16);
    pk.y = (unsigned)f2bf(wa.z) | ((unsigned)f2bf(wa.w) << 16);
    pk.z = (unsigned)f2bf(wb.x) | ((unsigned)f2bf(wb.y) << 16);
    pk.w = (unsigned)f2bf(wb.z) | ((unsigned)f2bf(wb.w) << 16);
    *(uint4*)(sBF + seg * 8) = pk;
  }

  // ---------------- Phase 2: V-scan. Wave wv covers sV rows [wv*44, +44);
  // 140 uniform steps (96 warm-up). Identical math to verified r2 body,
  // re-paired as f32x2 (sum reassociation only).
  {
    float v = 0.f;
    int base = wv * 44;
    const f32x2 z2 = {0.f, 0.f};
    auto STEP = [&](float ut) {
      f32x2 v2 = {v, v}, u2 = {ut, ut};
      f32x2 q0 = __builtin_elementwise_max(
          __builtin_elementwise_fma(v2, rp2[0], u2 * ip2[0]), z2) * rr2[0];
      f32x2 q1 = __builtin_elementwise_max(
          __builtin_elementwise_fma(v2, rp2[1], u2 * ip2[1]), z2) * rr2[1];
      f32x2 q2 = __builtin_elementwise_max(
          __builtin_elementwise_fma(v2, rp2[2], u2 * ip2[2]), z2) * rr2[2];
      f32x2 q3 = __builtin_elementwise_max(
          __builtin_elementwise_fma(v2, rp2[3], u2 * ip2[3]), z2) * rr2[3];
      f32x2 s2 = (q0 + q1) + (q2 + q3);
      float s = s2[0] + s2[1];
      ROR_ADD(s, 0x121); ROR_ADD(s, 0x122); ROR_ADD(s, 0x124); ROR_ADD(s, 0x128);
      float tot = __int_as_float(__builtin_amdgcn_readlane(__float_as_int(s), 0)) +
                  __int_as_float(__builtin_amdgcn_readlane(__float_as_int(s), 16)) +
                  __int_as_float(__builtin_amdgcn_readlane(__float_as_int(s), 32)) +
                  __int_as_float(__builtin_amdgcn_readlane(__float_as_int(s), 48));
      v = fmaf(0.9f, v, 0.1f * tot);
    };
    #pragma unroll 4
    for (int i = 0; i < 96; i++) STEP(su[base + i]);          // warm-up
    #pragma unroll 4
    for (int k = 0; k < 44; k++) {                            // real rows
      if (lane == 0) sV[base + k] = v;                        // v entering step
      STEP(su[base + 96 + k]);
    }
  }
  __syncthreads();   // sV + sBF ready

  // ---------------- Phase 3: w rows [0,352) via MFMA; 3 m-tiles/wave
  {
    int tl = lane & 15, quad = lane >> 4;
    float Vr[3], ur[3];
    #pragma unroll
    for (int m = 0; m < 3; m++) {
      int row = (wv * 3 + m) * 16 + tl;   // 0..383 (>=352: zero pad, discarded)
      Vr[m] = sV[row];
      ur[m] = su[96 + row];
    }
    f32x4 acc[3][4] = {};  // [m][ot]
    #pragma unroll 4
    for (int kt = 0; kt < 16; kt++) {
      int hbase = kt * 32 + quad * 8;
      f32x4 rp4a = *(const f32x4*)(srp + hbase);
      f32x4 rp4b = *(const f32x4*)(srp + hbase + 4);
      f32x4 ip4a = *(const f32x4*)(sip + hbase);
      f32x4 ip4b = *(const f32x4*)(sip + hbase + 4);
      bf16x8 bfr[4];
      #pragma unroll
      for (int ot = 0; ot < 4; ot++)
        bfr[ot] = *(const bf16x8*)(sBF + (((kt * 4 + ot) * 64 + lane) << 3));
      #pragma unroll
      for (int m = 0; m < 3; m++) {
        float q[8];
        #pragma unroll
        for (int j = 0; j < 4; j++) {
          q[j]     = fmaxf(fmaf(Vr[m], rp4a[j], ur[m] * ip4a[j]), 0.f);
          q[4 + j] = fmaxf(fmaf(Vr[m], rp4b[j], ur[m] * ip4b[j]), 0.f);
        }
        union { bf16x8 v; unsigned w[4]; } a;
        #pragma unroll
        for (int j = 0; j < 4; j++) a.w[j] = pack_bf(q[2 * j], q[2 * j + 1]);
        #pragma unroll
        for (int ot = 0; ot < 4; ot++)
          acc[m][ot] = __builtin_amdgcn_mfma_f32_16x16x32_bf16(a.v, bfr[ot], acc[m][ot], 0, 0, 0);
      }
    }
    // C/D layout: col = ot*16 + tl (o), row-in-tile = quad*4 + r (t offset)
    #pragma unroll
    for (int m = 0; m < 3; m++) {
      int mt = wv * 3 + m;
      if (mt < 22) {
        int rbase = mt * 16 + quad * 4;
        #pragma unroll
        for (int r = 0; r < 4; r++) {
          #pragma unroll
          for (int ot = 0; ot < 4; ot++)
            sw[swz(rbase + r, ot * 16 + tl)] = f2bf(acc[m][ot][r]);
        }
      }
    }
  }
  __syncthreads();

  // ---------------- Phase 4: y-scan. Wave wv owns outputs [r0+wv*32, +32);
  // scans sw rows [wv*32, +128) (rows with t<0 are exactly 0 -> uniform loop).
  {
    float y = 0.f;
    float bo = bias[lane];
    int k0 = wv * 32;
    float* ob = out + ((size_t)(b * S_ + r0 + k0)) * O_ + lane;
    #pragma unroll 8
    for (int i = 0; i < 96; i++)
      y = fmaf(0.9f, y, 0.1f * bf2f(sw[swz(k0 + i, lane)]));
    #pragma unroll 4
    for (int i = 0; i < 32; i++) {
      y = fmaf(0.9f, y, 0.1f * bf2f(sw[swz(k0 + 96 + i, lane)]));
      ob[(size_t)i * O_] = y + bo;
    }
  }
}

extern "C" void kernel_launch(void* const* d_in, const int* in_sizes, int n_in,
                              void* d_out, int out_size, void* d_ws, size_t ws_size,
                              hipStream_t stream) {
  const float* x   = (const float*)d_in[0];
  const float* ipj = (const float*)d_in[1];
  const float* irc = (const float*)d_in[2];
  const float* rpj = (const float*)d_in[3];
  const float* rrc = (const float*)d_in[4];
  const float* Wr  = (const float*)d_in[5];
  const float* br  = (const float*)d_in[6];
  float* out = (float*)d_out;

  static bool s_init = false;
  if (!s_init) {
    hipFuncSetAttribute((const void*)k_fused,
                        hipFuncAttributeMaxDynamicSharedMemorySize, SMEM_BYTES);
    s_init = true;
  }
  k_fused<<<dim3(256), dim3(512), SMEM_BYTES, stream>>>(x, ipj, irc, rpj, rrc,
                                                        Wr, br, out);
}

// Round 5
// 129.774 us; speedup vs baseline: 2.3645x; 1.1504x over previous
//
#include <hip/hip_runtime.h>

// B=32, S=2048, I=128, H=512, O=64, R=1, ALPHA=0.1  (rank-1 scalar-state RNN)
// Single dispatch, 256 blocks x 512 threads (8 waves), 1 block/CU.
// Block owns 256 output timesteps of one batch; recomputes 96-step warm-up.
// Round-3 lesson: lambda(float4*) took the address of local arrays -> scratch
// spill (WRITE_SIZE 70MB vs 17MB ideal). Round-4 lesson: srp[tid+256] staging
// under 512 threads raced into sip[0..255] (absmax 4.5e-2) -- with 512 threads
// each thread stages exactly ONE srp/sip element.
//   ph1: u[t] = x[t,:].irc for t in [r0-192,r0+256); global_load_lds (16B) with
//        counted vmcnt, 3-slot pipeline, per-wave stripes (no syncthreads)
//   ph2: 8 waves x 44-t V-chunks, 140 uniform steps (96 warm-up), med3-clamp
//        with 0.1*rr folded into pre-relu coefficients (relu pos-homogeneous)
//   ph3: w rows [0,352) = relu(V*rp+u*ip) @ W^T via 16x16x32 bf16 MFMA -> sw
//   ph4: y-scan, 8 waves x 32 outputs, 96-step warm-up (rows t<0 are zero)

#define B_ 32
#define S_ 2048
#define I_ 128
#define H_ 512
#define O_ 64

typedef __attribute__((ext_vector_type(8))) short bf16x8;
typedef __attribute__((ext_vector_type(4))) float f32x4;
typedef __attribute__((ext_vector_type(2))) float f32x2;

__device__ __forceinline__ unsigned short f2bf(float f) {
  unsigned int b = __float_as_uint(f);
  b += 0x7FFFu + ((b >> 16) & 1u);
  return (unsigned short)(b >> 16);
}
__device__ __forceinline__ float bf2f(unsigned short s) {
  return __uint_as_float(((unsigned)s) << 16);
}
__device__ __forceinline__ unsigned pack_bf(float lo, float hi) {
  unsigned a = (__float_as_uint(lo) + 0x8000u) >> 16;
  unsigned b = (__float_as_uint(hi) + 0x8000u) & 0xFFFF0000u;
  return a | b;
}

// DPP row-rotate add (16-lane rows). ror 1,2,4 -> 8-sums valid at in-row
// positions 7/15; ror 1,2,4,8 -> full 16-sum in every lane. (verified r0-r3)
#define ROR_ADD(s, CTRL) \
  s += __int_as_float(__builtin_amdgcn_update_dpp(0, __float_as_int(s), CTRL, 0xF, 0xF, true))

#define RL(s, L) __int_as_float(__builtin_amdgcn_readlane(__float_as_int(s), (L)))

// async global->LDS, 16B/lane; LDS dest = uniform base + lane*16 (HW rule)
__device__ __forceinline__ void gload16(const void* g, void* l) {
  __builtin_amdgcn_global_load_lds(
      (const __attribute__((address_space(1))) unsigned int*)g,
      (__attribute__((address_space(3))) unsigned int*)l, 16, 0, 0);
}
#define WAITVM(N) asm volatile("s_waitcnt vmcnt(" #N ")" ::: "memory")

// LDS layout (bytes): su[480]f | sV[384]f | srp[512]f | sip[512]f |
//   sw[352*64]ush | xs: 3 x 32768 x-slots (ph1) aliased by sBF[32768]ush (ph3)
#define OFF_SU 0
#define OFF_SV 1920
#define OFF_RP 3456
#define OFF_IP 5504
#define OFF_SW 7552
#define OFF_XS 52608
#define SMEM_BYTES 150912

// sw bank-swizzle (verified r0-r3): row stride 128 B; XOR col bits 4-5 with
// (row>>2)&3 (== quad in ph3) spreads quads across banks.
__device__ __forceinline__ int swz(int row, int col) {
  return row * 64 + (col ^ ((((unsigned)row >> 2) & 3) << 4));
}

__global__ __launch_bounds__(512, 1) void k_fused(
    const float* __restrict__ x, const float* __restrict__ ipj,
    const float* __restrict__ irc, const float* __restrict__ rpj,
    const float* __restrict__ rrc, const float* __restrict__ Wr,
    const float* __restrict__ bias, float* __restrict__ out) {
  extern __shared__ __align__(16) char smem[];
  float* su = (float*)(smem + OFF_SU);
  float* sV = (float*)(smem + OFF_SV);
  float* srp = (float*)(smem + OFF_RP);
  float* sip = (float*)(smem + OFF_IP);
  unsigned short* sw = (unsigned short*)(smem + OFF_SW);
  unsigned short* sBF = (unsigned short*)(smem + OFF_XS);
  float* xsf = (float*)(smem + OFF_XS);

  const int tid = threadIdx.x;
  const int wv = tid >> 6;      // 0..7
  const int lane = tid & 63;
  const int b = blockIdx.x >> 3;
  const int g = blockIdx.x & 7;
  const int r0 = g * 256;

  // ---- top preloads (oldest in VMEM FIFO; retired by ph1's counted waits) ----
  // ph1 dot: lane handles row (wv*8 + (lane>>3)), col segs (lane&7)+8i, i=0..3
  f32x4 cv0 = *(const f32x4*)(irc + 4 * (lane & 7));
  f32x4 cv1 = *(const f32x4*)(irc + 4 * (lane & 7) + 32);
  f32x4 cv2 = *(const f32x4*)(irc + 4 * (lane & 7) + 64);
  f32x4 cv3 = *(const f32x4*)(irc + 4 * (lane & 7) + 96);
  // ph2 params: h-pair = 2*(lane+64k), +1. Fold 0.1*rr into a,b; sign via clamp:
  // 0.1*rr*relu(rp*v+ip*u) = clamp(a*v+b*u, lo, hi), a=0.1*rr*rp, b=0.1*rr*ip,
  // (lo,hi) = (0,+inf) if rr>0 else (-inf,0).   [relu positively homogeneous]
  f32x2 a2[4], b2[4], lo2[4], hi2[4];
  #pragma unroll
  for (int k = 0; k < 4; k++) {
    float2 rp = ((const float2*)rpj)[lane + 64 * k];
    float2 ip = ((const float2*)ipj)[lane + 64 * k];
    float2 rr = ((const float2*)rrc)[lane + 64 * k];
    a2[k] = f32x2{0.1f * rr.x * rp.x, 0.1f * rr.y * rp.y};
    b2[k] = f32x2{0.1f * rr.x * ip.x, 0.1f * rr.y * ip.y};
    lo2[k] = f32x2{rr.x > 0.f ? 0.f : -__builtin_inff(),
                   rr.y > 0.f ? 0.f : -__builtin_inff()};
    hi2[k] = f32x2{rr.x > 0.f ? __builtin_inff() : 0.f,
                   rr.y > 0.f ? __builtin_inff() : 0.f};
  }
  if (tid < 32) { su[448 + tid] = 0.f; sV[352 + tid] = 0.f; }

  // ---------------- Phase 1: x window [r0-192,r0+256) -> su via gll pipeline.
  // Chunk c = 64 rows (32 KB). Wave stages its own rows [wv*8,+8) (4 gll calls,
  // 1 KB each) into slot c%3 and consumes only those -> no syncthreads needed.
  // Chunks with t<0 are whole-chunk masked (window start is 64-aligned).
#define ISSUE(c) do { \
    int tc_ = r0 - 192 + (c) * 64 + wv * 8; if (tc_ < 0) tc_ = 0; \
    const float* gs_ = x + ((size_t)b * S_ + tc_) * I_ + lane * 4; \
    char* ld_ = (char*)xsf + ((c) % 3) * 32768 + wv * 4096; \
    gload16(gs_,       ld_); \
    gload16(gs_ + 256, ld_ + 1024); \
    gload16(gs_ + 512, ld_ + 2048); \
    gload16(gs_ + 768, ld_ + 3072); \
  } while (0)

#define COMPUTE(c) do { \
    const float* bp_ = xsf + ((c) % 3) * 8192 + (wv * 8 + (lane >> 3)) * 128 + (lane & 7) * 4; \
    f32x4 x0_ = *(const f32x4*)(bp_); \
    f32x4 x1_ = *(const f32x4*)(bp_ + 32); \
    f32x4 x2_ = *(const f32x4*)(bp_ + 64); \
    f32x4 x3_ = *(const f32x4*)(bp_ + 96); \
    float p0_ = x0_[0] * cv0[0], p1_ = x0_[1] * cv0[1]; \
    float p2_ = x0_[2] * cv0[2], p3_ = x0_[3] * cv0[3]; \
    p0_ = fmaf(x1_[0], cv1[0], p0_); p1_ = fmaf(x1_[1], cv1[1], p1_); \
    p2_ = fmaf(x1_[2], cv1[2], p2_); p3_ = fmaf(x1_[3], cv1[3], p3_); \
    p0_ = fmaf(x2_[0], cv2[0], p0_); p1_ = fmaf(x2_[1], cv2[1], p1_); \
    p2_ = fmaf(x2_[2], cv2[2], p2_); p3_ = fmaf(x2_[3], cv2[3], p3_); \
    p0_ = fmaf(x3_[0], cv3[0], p0_); p1_ = fmaf(x3_[1], cv3[1], p1_); \
    p2_ = fmaf(x3_[2], cv3[2], p2_); p3_ = fmaf(x3_[3], cv3[3], p3_); \
    float s_ = (p0_ + p1_) + (p2_ + p3_); \
    ROR_ADD(s_, 0x121); ROR_ADD(s_, 0x122); ROR_ADD(s_, 0x124); \
    float mask_ = (r0 - 192 + (c) * 64 >= 0) ? 1.f : 0.f; \
    if ((lane & 7) == 7) su[(c) * 64 + wv * 8 + (lane >> 3)] = s_ * mask_; \
  } while (0)

  ISSUE(0); ISSUE(1); ISSUE(2);
  WAITVM(8); COMPUTE(0); ISSUE(3);
  WAITVM(8); COMPUTE(1); ISSUE(4);
  WAITVM(8); COMPUTE(2); ISSUE(5);
  WAITVM(8); COMPUTE(3); ISSUE(6);
  WAITVM(8); COMPUTE(4);
  WAITVM(4); COMPUTE(5);
  WAITVM(0); COMPUTE(6);
  __syncthreads();   // su complete; x slots dead

  // ---- W preload to registers (static-indexed, stays in VGPRs); converted
  // after ph2 so the 16 L2 loads hide under the scan. Frag map (verified r0-r3):
  // sBF[((kt*4+ot)*64+l2)*8+j] = bf(W[(ot*16+(l2&15))*H + kt*32+(l2>>4)*8+j])
  float4 wA0, wB0, wA1, wB1, wA2, wB2, wA3, wB3;
  float4 wA4, wB4, wA5, wB5, wA6, wB6, wA7, wB7;
#define WLOAD(m, A, Bv) do { \
    int seg_ = tid + 512 * (m); \
    int l2_ = seg_ & 63, ot_ = (seg_ >> 6) & 3, kt_ = seg_ >> 8; \
    const float4* wp_ = (const float4*)(Wr + (size_t)(ot_ * 16 + (l2_ & 15)) * H_ + kt_ * 32 + (l2_ >> 4) * 8); \
    A = wp_[0]; Bv = wp_[1]; \
  } while (0)
  WLOAD(0, wA0, wB0); WLOAD(1, wA1, wB1); WLOAD(2, wA2, wB2); WLOAD(3, wA3, wB3);
  WLOAD(4, wA4, wB4); WLOAD(5, wA5, wB5); WLOAD(6, wA6, wB6); WLOAD(7, wA7, wB7);
  // 512 threads -> each thread stages exactly ONE srp/sip element (r4 bugfix)
  float rpa = rpj[tid];
  float ipa = ipj[tid];

  // ---------------- Phase 2: V-scan. Wave wv covers sV rows [wv*44,+44);
  // 140 uniform steps (96 warm-up). tot is pre-scaled by 0.1 (folded above).
#define VSTEP(UT) do { \
    float ut_ = (UT); \
    f32x2 v2_ = {v, v}, u2_ = {ut_, ut_}; \
    f32x2 c0_ = __builtin_elementwise_min(__builtin_elementwise_max( \
        __builtin_elementwise_fma(v2_, a2[0], u2_ * b2[0]), lo2[0]), hi2[0]); \
    f32x2 c1_ = __builtin_elementwise_min(__builtin_elementwise_max( \
        __builtin_elementwise_fma(v2_, a2[1], u2_ * b2[1]), lo2[1]), hi2[1]); \
    f32x2 c2_ = __builtin_elementwise_min(__builtin_elementwise_max( \
        __builtin_elementwise_fma(v2_, a2[2], u2_ * b2[2]), lo2[2]), hi2[2]); \
    f32x2 c3_ = __builtin_elementwise_min(__builtin_elementwise_max( \
        __builtin_elementwise_fma(v2_, a2[3], u2_ * b2[3]), lo2[3]), hi2[3]); \
    f32x2 s2_ = (c0_ + c1_) + (c2_ + c3_); \
    float s_ = s2_[0] + s2_[1]; \
    ROR_ADD(s_, 0x121); ROR_ADD(s_, 0x122); ROR_ADD(s_, 0x124); ROR_ADD(s_, 0x128); \
    float tot_ = (RL(s_, 0) + RL(s_, 16)) + (RL(s_, 32) + RL(s_, 48)); \
    v = fmaf(0.9f, v, tot_); \
  } while (0)
  {
    float v = 0.f;
    int base = wv * 44;
    #pragma unroll 4
    for (int i = 0; i < 96; i++) VSTEP(su[base + i]);         // warm-up
    #pragma unroll 4
    for (int k = 0; k < 44; k++) {                            // real rows
      if (lane == 0) sV[base + k] = v;                        // v entering step
      VSTEP(su[base + 96 + k]);
    }
  }

  // ---- convert W regs -> sBF (aliases dead x slots), stage srp/sip ----
#define WPACK(m, A, Bv) do { \
    int seg_ = tid + 512 * (m); \
    uint4 pk_; \
    pk_.x = (unsigned)f2bf(A.x) | ((unsigned)f2bf(A.y) << 16); \
    pk_.y = (unsigned)f2bf(A.z) | ((unsigned)f2bf(A.w) << 16); \
    pk_.z = (unsigned)f2bf(Bv.x) | ((unsigned)f2bf(Bv.y) << 16); \
    pk_.w = (unsigned)f2bf(Bv.z) | ((unsigned)f2bf(Bv.w) << 16); \
    *(uint4*)(sBF + seg_ * 8) = pk_; \
  } while (0)
  WPACK(0, wA0, wB0); WPACK(1, wA1, wB1); WPACK(2, wA2, wB2); WPACK(3, wA3, wB3);
  WPACK(4, wA4, wB4); WPACK(5, wA5, wB5); WPACK(6, wA6, wB6); WPACK(7, wA7, wB7);
  srp[tid] = rpa;
  sip[tid] = ipa;
  __syncthreads();   // sV + sBF + srp/sip ready

  // ---------------- Phase 3: w rows [0,352) via MFMA; 3 m-tiles/wave
  {
    int tl = lane & 15, quad = lane >> 4;
    float Vr0 = sV[(wv * 3 + 0) * 16 + tl], ur0 = su[96 + (wv * 3 + 0) * 16 + tl];
    float Vr1 = sV[(wv * 3 + 1) * 16 + tl], ur1 = su[96 + (wv * 3 + 1) * 16 + tl];
    float Vr2 = sV[(wv * 3 + 2) * 16 + tl], ur2 = su[96 + (wv * 3 + 2) * 16 + tl];
    f32x4 acc[3][4] = {};  // [m][ot]
    #pragma unroll 4
    for (int kt = 0; kt < 16; kt++) {
      int hbase = kt * 32 + quad * 8;
      f32x4 rp4a = *(const f32x4*)(srp + hbase);
      f32x4 rp4b = *(const f32x4*)(srp + hbase + 4);
      f32x4 ip4a = *(const f32x4*)(sip + hbase);
      f32x4 ip4b = *(const f32x4*)(sip + hbase + 4);
      bf16x8 bfr0 = *(const bf16x8*)(sBF + (((kt * 4 + 0) * 64 + lane) << 3));
      bf16x8 bfr1 = *(const bf16x8*)(sBF + (((kt * 4 + 1) * 64 + lane) << 3));
      bf16x8 bfr2 = *(const bf16x8*)(sBF + (((kt * 4 + 2) * 64 + lane) << 3));
      bf16x8 bfr3 = *(const bf16x8*)(sBF + (((kt * 4 + 3) * 64 + lane) << 3));
      #pragma unroll
      for (int m = 0; m < 3; m++) {
        float Vm = m == 0 ? Vr0 : (m == 1 ? Vr1 : Vr2);
        float um = m == 0 ? ur0 : (m == 1 ? ur1 : ur2);
        float q[8];
        #pragma unroll
        for (int j = 0; j < 4; j++) {
          q[j]     = fmaxf(fmaf(Vm, rp4a[j], um * ip4a[j]), 0.f);
          q[4 + j] = fmaxf(fmaf(Vm, rp4b[j], um * ip4b[j]), 0.f);
        }
        union { bf16x8 v; unsigned w[4]; } a;
        #pragma unroll
        for (int j = 0; j < 4; j++) a.w[j] = pack_bf(q[2 * j], q[2 * j + 1]);
        acc[m][0] = __builtin_amdgcn_mfma_f32_16x16x32_bf16(a.v, bfr0, acc[m][0], 0, 0, 0);
        acc[m][1] = __builtin_amdgcn_mfma_f32_16x16x32_bf16(a.v, bfr1, acc[m][1], 0, 0, 0);
        acc[m][2] = __builtin_amdgcn_mfma_f32_16x16x32_bf16(a.v, bfr2, acc[m][2], 0, 0, 0);
        acc[m][3] = __builtin_amdgcn_mfma_f32_16x16x32_bf16(a.v, bfr3, acc[m][3], 0, 0, 0);
      }
    }
    // C/D layout: col = ot*16 + tl (o), row-in-tile = quad*4 + r (t offset)
    #pragma unroll
    for (int m = 0; m < 3; m++) {
      int mt = wv * 3 + m;
      if (mt < 22) {
        int rbase = mt * 16 + quad * 4;
        #pragma unroll
        for (int r = 0; r < 4; r++) {
          #pragma unroll
          for (int ot = 0; ot < 4; ot++)
            sw[swz(rbase + r, ot * 16 + tl)] = f2bf(acc[m][ot][r]);
        }
      }
    }
  }
  __syncthreads();

  // ---------------- Phase 4: y-scan. Wave wv owns outputs [r0+wv*32,+32);
  // scans sw rows [wv*32,+128) (rows with t<0 are exactly 0 -> uniform loop).
  {
    float y = 0.f;
    float bo = bias[lane];
    int k0 = wv * 32;
    float* ob = out + ((size_t)(b * S_ + r0 + k0)) * O_ + lane;
    #pragma unroll 8
    for (int i = 0; i < 96; i++)
      y = fmaf(0.9f, y, 0.1f * bf2f(sw[swz(k0 + i, lane)]));
    #pragma unroll 4
    for (int i = 0; i < 32; i++) {
      y = fmaf(0.9f, y, 0.1f * bf2f(sw[swz(k0 + 96 + i, lane)]));
      ob[(size_t)i * O_] = y + bo;
    }
  }
}

extern "C" void kernel_launch(void* const* d_in, const int* in_sizes, int n_in,
                              void* d_out, int out_size, void* d_ws, size_t ws_size,
                              hipStream_t stream) {
  const float* x   = (const float*)d_in[0];
  const float* ipj = (const float*)d_in[1];
  const float* irc = (const float*)d_in[2];
  const float* rpj = (const float*)d_in[3];
  const float* rrc = (const float*)d_in[4];
  const float* Wr  = (const float*)d_in[5];
  const float* br  = (const float*)d_in[6];
  float* out = (float*)d_out;

  static bool s_init = false;
  if (!s_init) {
    hipFuncSetAttribute((const void*)k_fused,
                        hipFuncAttributeMaxDynamicSharedMemorySize, SMEM_BYTES);
    s_init = true;
  }
  k_fused<<<dim3(256), dim3(512), SMEM_BYTES, stream>>>(x, ipj, irc, rpj, rrc,
                                                        Wr, br, out);
}